// Round 4
// baseline (1758.411 us; speedup 1.0000x reference)
//
#include <hip/hip_runtime.h>
#include <stdint.h>

// ROUND 4: pure-scalar f32 correctness baseline (bisection anchor).
// No MFMA, no dynamic LDS, 12 MB ws. Mirrors the reference einsums directly.
//
// K1 qkv_scalar:  block=(z,b*l), 512 thr; thread t = output feature o.
//                 q/k/v stored (B,H,L,DH) f32 in ws.
// K2 attn_scalar: block=(b,q), 512 thr = (h=t>>6, lane=t&63); all 8 heads per
//                 block so rels[b,q,:,:] is reused 8x via cache.
//                 phase1 scores -> LDS, phase2 per-wave softmax,
//                 phase3 ctx = sum_k P*(v + rels), coalesced.
//
// Bisect plan: if PASS, re-introduce MFMA kernels one per round.

typedef unsigned short u16;

// ---------------------------------------------------------------- K1 ---
__global__ __launch_bounds__(512)
void qkv_scalar(const float* __restrict__ X,
                const float* __restrict__ Wq, const float* __restrict__ bq,
                const float* __restrict__ Wk, const float* __restrict__ bk,
                const float* __restrict__ Wv, const float* __restrict__ bv,
                float* __restrict__ qf, float* __restrict__ kf, float* __restrict__ vf)
{
    __shared__ float Xs[512];
    const int z  = blockIdx.y;            // 0=q 1=k 2=v
    const int bl = blockIdx.x;            // b*512 + l
    const float* W  = (z==0) ? Wq : (z==1) ? Wk : Wv;
    const float* bb = (z==0) ? bq : (z==1) ? bk : bv;
    float* dst      = (z==0) ? qf : (z==1) ? kf : vf;

    const int t = threadIdx.x;            // output feature o = t
    Xs[t] = X[(size_t)bl*512 + t];
    __syncthreads();

    const float* wrow = W + (size_t)t*512;
    float a0=0.f, a1=0.f, a2=0.f, a3=0.f;
    #pragma unroll 4
    for (int k=0; k<512; k+=4) {
        a0 = fmaf(Xs[k+0], wrow[k+0], a0);
        a1 = fmaf(Xs[k+1], wrow[k+1], a1);
        a2 = fmaf(Xs[k+2], wrow[k+2], a2);
        a3 = fmaf(Xs[k+3], wrow[k+3], a3);
    }
    const float acc = bb[t] + ((a0+a1)+(a2+a3));

    const int b = bl >> 9, l = bl & 511;
    const int h = t >> 6,  d = t & 63;
    dst[((size_t)(b*8 + h)*512 + l)*64 + d] = acc;   // (B,H,L,DH)
}

// ---------------------------------------------------------------- K2 ---
__global__ __launch_bounds__(512)
void attn_scalar(const float* __restrict__ qf, const float* __restrict__ kf,
                 const float* __restrict__ vf, const float* __restrict__ rels,
                 const float* __restrict__ heads, float* __restrict__ out)
{
    __shared__ float S[8*512];            // scores/probs per head (16 KB)
    __shared__ float qs[8*64];            // q rows (2 KB)

    const int bq = blockIdx.x;            // b*512 + q
    const int b = bq >> 9, q = bq & 511;
    const int t = threadIdx.x;
    const int h = t >> 6, lane = t & 63;

    qs[t] = qf[((size_t)(b*8 + (t>>6))*512 + q)*64 + (t & 63)];
    __syncthreads();

    const float* qrow = qs + h*64;

    // phase 1: scores. thread (h,lane) covers k = lane + 64*k8
    for (int k8 = 0; k8 < 8; k8++) {
        const int k = k8*64 + lane;
        const float* krow = kf   + ((size_t)(b*8 + h)*512 + k)*64;
        const float* rrow = rels + ((size_t)(b*512 + q)*512 + k)*64;
        float a0=0.f, a1=0.f;
        #pragma unroll 8
        for (int d=0; d<64; d++) {
            const float qd = qrow[d];
            a0 = fmaf(qd, krow[d], a0);
            a1 = fmaf(qd, rrow[d], a1);
        }
        S[h*512 + k] = (a0 + a1)*0.125f + heads[((size_t)b*512 + q)*512 + k];
    }
    // no barrier needed: each thread reads back only slots it wrote, plus
    // wave-level shuffles; S rows are private to wave h.

    // phase 2: softmax over row h (wave h owns it)
    float m = -3.0e38f;
    #pragma unroll
    for (int i=0;i<8;i++) m = fmaxf(m, S[h*512 + lane + 64*i]);
    #pragma unroll
    for (int w=1; w<64; w<<=1) m = fmaxf(m, __shfl_xor(m, w));
    float sum = 0.f;
    #pragma unroll
    for (int i=0;i<8;i++) {
        const float e = __expf(S[h*512 + lane + 64*i] - m);
        S[h*512 + lane + 64*i] = e;
        sum += e;
    }
    #pragma unroll
    for (int w=1; w<64; w<<=1) sum += __shfl_xor(sum, w);
    const float inv = 1.f / sum;

    // phase 3: ctx[b,q,h*64+d] = sum_k P[h,k]*(v[b,h,k,d] + rels[b,q,k,d])
    const int d = lane;
    const float* vbase = vf   + ((size_t)(b*8 + h)*512)*64 + d;
    const float* rbase = rels + ((size_t)(b*512 + q)*512)*64 + d;
    const float* Ph = S + h*512;
    float c0=0.f, c1=0.f, c2=0.f, c3=0.f;
    for (int k=0; k<512; k+=4) {
        c0 = fmaf(Ph[k+0], vbase[(size_t)(k+0)*64] + rbase[(size_t)(k+0)*64], c0);
        c1 = fmaf(Ph[k+1], vbase[(size_t)(k+1)*64] + rbase[(size_t)(k+1)*64], c1);
        c2 = fmaf(Ph[k+2], vbase[(size_t)(k+2)*64] + rbase[(size_t)(k+2)*64], c2);
        c3 = fmaf(Ph[k+3], vbase[(size_t)(k+3)*64] + rbase[(size_t)(k+3)*64], c3);
    }
    out[((size_t)b*512 + q)*512 + h*64 + d] = ((c0+c1)+(c2+c3)) * inv;
}

// --------------------------------------------------------------- launcher ---
extern "C" void kernel_launch(void* const* d_in, const int* in_sizes, int n_in,
                              void* d_out, int out_size, void* d_ws, size_t ws_size,
                              hipStream_t stream)
{
    (void)in_sizes; (void)n_in; (void)out_size; (void)ws_size;

    const float* hidden = (const float*)d_in[0];
    const float* heads  = (const float*)d_in[1];
    const float* rels   = (const float*)d_in[2];
    const float* Wq = (const float*)d_in[3];
    const float* bq = (const float*)d_in[4];
    const float* Wk = (const float*)d_in[5];
    const float* bk = (const float*)d_in[6];
    const float* Wv = (const float*)d_in[7];
    const float* bv = (const float*)d_in[8];
    float* outF = (float*)d_out;

    float* ws = (float*)d_ws;
    float* qf = ws;                 // (B,H,L,DH) = 1,048,576 f32 (4 MB)
    float* kf = ws + 1048576;       // 4 MB
    float* vf = ws + 2097152;       // 4 MB; total ws use = 12 MB

    qkv_scalar<<<dim3(2048, 3), 512, 0, stream>>>(
        hidden, Wq, bq, Wk, bk, Wv, bv, qf, kf, vf);

    attn_scalar<<<dim3(2048), 512, 0, stream>>>(qf, kf, vf, rels, heads, outF);
}